// Round 8
// baseline (176.758 us; speedup 1.0000x reference)
//
#include <hip/hip_runtime.h>
#include <hip/hip_bf16.h>

// HumanVAttention: QKV proj -> in-place RoPE -> V transpose -> GQA block-sparse attn -> out proj
// B=1 S=4096 HID=2048 NH=16 NKV=4 HD=128 BLK=64 LOCAL=4 GNB=2 STRIDE=4 ROT=64

typedef short short8 __attribute__((ext_vector_type(8)));
typedef float f32x4  __attribute__((ext_vector_type(4)));

#define NEGV   (-1.0e9f)
#define SCALE  (0.08838834764831845f)

__device__ __forceinline__ void gload16(const void* g, void* l) {
  __builtin_amdgcn_global_load_lds(
      (const __attribute__((address_space(1))) unsigned int*)g,
      (__attribute__((address_space(3))) unsigned int*)l, 16, 0, 0);
}

__device__ __forceinline__ float bf2f(short s) {
  union { unsigned u; float f; } c;
  c.u = ((unsigned)(unsigned short)s) << 16;
  return c.f;
}

__device__ __forceinline__ short f2bf_s(float f) {
  __hip_bfloat16 b = __float2bfloat16(f);
  short s;
  __builtin_memcpy(&s, &b, 2);
  return s;
}

// ---------------- elementwise convert hidden f32 -> bf16 ----------------
__global__ void conv_hidden(const float* __restrict__ H, __hip_bfloat16* __restrict__ X) {
  size_t t = (size_t)blockIdx.x * 256 + threadIdx.x;   // one float4 per thread
  float4 v = *(const float4*)(H + t * 4);
  __hip_bfloat16* o = X + t * 4;
  o[0] = __float2bfloat16(v.x); o[1] = __float2bfloat16(v.y);
  o[2] = __float2bfloat16(v.z); o[3] = __float2bfloat16(v.w);
}

// ---------------- tiled transpose f32[R][C] -> bf16 dst[C][R] ----------------
__global__ void transpose_f32_to_bf16(const float* __restrict__ src,
                                      __hip_bfloat16* __restrict__ dst,
                                      int R, int C) {
  __shared__ __hip_bfloat16 tile[64][73];
  int r0 = blockIdx.x * 64, c0 = blockIdx.y * 64;
  int c = threadIdx.x & 63, rq = threadIdx.x >> 6;
#pragma unroll
  for (int i = 0; i < 16; ++i) {
    int r = i * 4 + rq;
    tile[r][c] = __float2bfloat16(src[(size_t)(r0 + r) * C + c0 + c]);
  }
  __syncthreads();
#pragma unroll
  for (int i = 0; i < 16; ++i) {
    int cc = i * 4 + rq;
    dst[(size_t)(c0 + cc) * R + r0 + c] = tile[c][cc];
  }
}

// ---------------- V transpose: Vb[s][c] (bf16, [4096][512]) -> Vt[c][s] ----------------
__global__ void transpose_v(const __hip_bfloat16* __restrict__ Vb,
                            __hip_bfloat16* __restrict__ Vt) {
  __shared__ __hip_bfloat16 tile[64][73];
  int s0 = blockIdx.x * 64, c0 = blockIdx.y * 64;
  int c = threadIdx.x & 63, rq = threadIdx.x >> 6;
#pragma unroll
  for (int i = 0; i < 16; ++i) {
    int r = i * 4 + rq;
    tile[r][c] = Vb[(size_t)(s0 + r) * 512 + c0 + c];
  }
  __syncthreads();
#pragma unroll
  for (int i = 0; i < 16; ++i) {
    int cc = i * 4 + rq;
    Vt[(size_t)(c0 + cc) * 4096 + s0 + c] = tile[c][cc];
  }
}

// ---------------- in-place partial RoPE on Qb and Kb (verified R6) ----------------
__global__ void rope_inplace(const float* __restrict__ cosb, const float* __restrict__ sinb,
                             __hip_bfloat16* __restrict__ Qb, __hip_bfloat16* __restrict__ Kb) {
  int t = blockIdx.x * 256 + threadIdx.x;
  __hip_bfloat16* p;
  int s;
  if (t < 262144) {               // Q: s = t>>6, then 16 h x 4 g
    s = t >> 6;
    int rem = t & 63;
    p = Qb + (size_t)s * 2048 + (rem >> 2) * 128 + (rem & 3) * 8;
  } else {                        // K: s = tk>>4, then 4 h x 4 g
    int tk = t - 262144;
    s = tk >> 4;
    int rem = tk & 15;
    p = Kb + (size_t)s * 512 + (rem >> 2) * 128 + (rem & 3) * 8;
  }
  const int g8 = (t & 3) * 8;     // d offset in [0,32)
  const float* cp = cosb + (size_t)s * 64 + g8;
  const float* sp = sinb + (size_t)s * 64 + g8;
  short8 a = *(const short8*)p;          // x[d],    d in [0,32)
  short8 b = *(const short8*)(p + 32);   // x[d+32]
  float ca[8], sa[8], cb[8], sb[8];
  *(float4*)&ca[0] = *(const float4*)cp;        *(float4*)&ca[4] = *(const float4*)(cp + 4);
  *(float4*)&cb[0] = *(const float4*)(cp + 32); *(float4*)&cb[4] = *(const float4*)(cp + 36);
  *(float4*)&sa[0] = *(const float4*)sp;        *(float4*)&sa[4] = *(const float4*)(sp + 4);
  *(float4*)&sb[0] = *(const float4*)(sp + 32); *(float4*)&sb[4] = *(const float4*)(sp + 36);
  short8 oa, ob;
#pragma unroll
  for (int i = 0; i < 8; ++i) {
    float av = bf2f(a[i]), bv = bf2f(b[i]);
    oa[i] = f2bf_s(av * ca[i] - bv * sa[i]);   // rot_half: d<32 -> -x[d+32]
    ob[i] = f2bf_s(bv * cb[i] + av * sb[i]);   // d>=32   -> +x[d-32]
  }
  *(short8*)p = oa;
  *(short8*)(p + 32) = ob;
}

// ---------------- GEMM1: 256x256 tile, 8-phase counted-vmcnt schedule (T2+T3+T4+T5) ----
// X[4096][2048] . Wt[3072][2048]^T -> Qb/Kb/Vb. 8 waves (2M x 4N), per-wave C 128x64.
// LDS 128 KiB = 2 buf x {A0,A1,B0,B1} half-tiles of 128x64 bf16 (16 KiB each).
// Stage order per tile tau: B0,B1,A0,A1 at phases 4tau..4tau+3; compute tile tau at
// phases 4tau+6..+9 (quadrant q per phase, 16 MFMA; bf hoisted at q0). One counted
// vmcnt(4) per tile at q3 (2 half-tiles stay in flight, never drains). Invariants:
// consumed halves are >=3 stage-slots old behind a barrier-separated vmcnt; a phase's
// stage never writes a region read in phases p-1..p+1 (B region of the compute buffer
// is dead after q0's hoist; A stages go to the other buffer).
__global__ __launch_bounds__(512, 2) void gemm_qkv8p(
    const __hip_bfloat16* __restrict__ A, const __hip_bfloat16* __restrict__ Bt,
    __hip_bfloat16* __restrict__ Qb, __hip_bfloat16* __restrict__ Kb,
    __hip_bfloat16* __restrict__ Vb) {
  const int K = 2048;
  const int tid = threadIdx.x;
  const int wave = tid >> 6, lane = tid & 63;
  const int l15 = lane & 15, lg = lane >> 4;
  const int bm = blockIdx.x, bn = blockIdx.y;
  const int wm = wave >> 2, wn = wave & 3;      // 2M x 4N

  __shared__ __hip_bfloat16 lds[65536];         // 128 KiB

  f32x4 acc[8][4] = {};
  const int srow = lane >> 3;                   // 0..7
  const int sslot = lane & 7;
  const int scol = (sslot ^ srow) * 8;          // pre-swizzled global col (row&7 == srow)
  const size_t abase = (size_t)bm * 256 * K;
  const size_t bbase = (size_t)bn * 256 * K;
  const int r3 = l15 & 7;

  // stage one 128x64 half-tile (16 KiB): 512 threads x 2 x gload16
#define STAGE_HALF(SRC, SBASE, HALF, KO, LBASE)                                  \
  do {                                                                           \
    _Pragma("unroll")                                                            \
    for (int l = 0; l < 2; ++l) {                                                \
      int chunk = l * 8 + wave;                                                  \
      int row = chunk * 8 + srow;                                                \
      gload16(SRC + (SBASE) + (size_t)((HALF) * 128 + row) * K + (KO) + scol,    \
              &lds[(LBASE) + chunk * 512]);                                      \
    }                                                                            \
  } while (0)

  // ---- prologue: B0(0),B1(0),A0(0),A1(0),B0(1),B1(1) ----
  STAGE_HALF(Bt, bbase, 0, 0, 16384);
  STAGE_HALF(Bt, bbase, 1, 0, 16384 + 8192);
  STAGE_HALF(A, abase, 0, 0, 0);
  STAGE_HALF(A, abase, 1, 0, 8192);
  STAGE_HALF(Bt, bbase, 0, 64, 32768 + 16384);
  STAGE_HALF(Bt, bbase, 1, 64, 32768 + 16384 + 8192);
  asm volatile("s_waitcnt vmcnt(4)" ::: "memory");
  __builtin_amdgcn_sched_barrier(0);
  __builtin_amdgcn_s_barrier();

  for (int t = 0; t < 32; ++t) {
    const int buf = (t & 1) * 32768;
    const int nbuf = buf ^ 32768;
    const int bA = buf + wm * 8192;
    const int bB = buf + 16384 + (wn >> 1) * 8192;
    short8 bfr[4][2];
#pragma unroll
    for (int q = 0; q < 4; ++q) {
      // ---- ds_read register subtile ----
      if (q == 0) {
#pragma unroll
        for (int ni = 0; ni < 4; ++ni)
#pragma unroll
          for (int ks = 0; ks < 2; ++ks) {
            int row = (wn & 1) * 64 + ni * 16 + l15;
            int slot = (ks * 4 + lg) ^ r3;
            bfr[ni][ks] = *(const short8*)&lds[bB + row * 64 + slot * 8];
          }
      }
      short8 af[2][2];
#pragma unroll
      for (int m2 = 0; m2 < 2; ++m2)
#pragma unroll
        for (int ks = 0; ks < 2; ++ks) {
          int row = (q * 2 + m2) * 16 + l15;
          int slot = (ks * 4 + lg) ^ r3;
          af[m2][ks] = *(const short8*)&lds[bA + row * 64 + slot * 8];
        }
      // ---- stage one half-tile ahead ----
      if (q == 0)      { if (t + 1 < 32) STAGE_HALF(A, abase, 0, (t + 1) * 64, nbuf); }
      else if (q == 1) { if (t + 1 < 32) STAGE_HALF(A, abase, 1, (t + 1) * 64, nbuf + 8192); }
      else if (q == 2) { if (t + 2 < 32) STAGE_HALF(Bt, bbase, 0, (t + 2) * 64, buf + 16384); }
      else {
        if (t + 2 < 32) STAGE_HALF(Bt, bbase, 1, (t + 2) * 64, buf + 16384 + 8192);
        if (t < 30) asm volatile("s_waitcnt vmcnt(4)" ::: "memory");
        else        asm volatile("s_waitcnt vmcnt(0)" ::: "memory");
        __builtin_amdgcn_sched_barrier(0);
      }
      __builtin_amdgcn_s_barrier();
      asm volatile("s_waitcnt lgkmcnt(0)" ::: "memory");
      __builtin_amdgcn_sched_barrier(0);
      __builtin_amdgcn_s_setprio(1);
#pragma unroll
      for (int ks = 0; ks < 2; ++ks)
#pragma unroll
        for (int m2 = 0; m2 < 2; ++m2)
#pragma unroll
          for (int ni = 0; ni < 4; ++ni)
            acc[q * 2 + m2][ni] = __builtin_amdgcn_mfma_f32_16x16x32_bf16(
                af[m2][ks], bfr[ni][ks], acc[q * 2 + m2][ni], 0, 0, 0);
      __builtin_amdgcn_s_setprio(0);
      __builtin_amdgcn_s_barrier();
    }
  }
#undef STAGE_HALF

  // ---- epilogue: bn tile (256 cols) maps wholly to Q (bn<8), K (8,9) or V (10,11) ----
  __hip_bfloat16* dst; int ldc, coff;
  if (bn < 8)       { dst = Qb; ldc = 2048; coff = bn * 256; }
  else if (bn < 10) { dst = Kb; ldc = 512;  coff = bn * 256 - 2048; }
  else              { dst = Vb; ldc = 512;  coff = bn * 256 - 2560; }
#pragma unroll
  for (int m8 = 0; m8 < 8; ++m8)
#pragma unroll
    for (int ni = 0; ni < 4; ++ni) {
      int row = bm * 256 + wm * 128 + m8 * 16 + lg * 4;
      int col = coff + wn * 64 + ni * 16 + l15;
#pragma unroll
      for (int r = 0; r < 4; ++r)
        dst[(size_t)(row + r) * ldc + col] = __float2bfloat16(acc[m8][ni][r]);
    }
}

// ---------------- GEMM2: C[M][N] f32 = A[M][K] bf16 . Bt[N][K]^T bf16 (verified 128^2) ----------------
__global__ __launch_bounds__(256) void gemm_bt(
    const __hip_bfloat16* __restrict__ A, const __hip_bfloat16* __restrict__ Bt,
    float* __restrict__ C, int M, int N, int K) {
  const int tid = threadIdx.x;
  const int wave = tid >> 6, lane = tid & 63;
  const int l15 = lane & 15, lg = lane >> 4;
  const int bm = blockIdx.x, bn = blockIdx.y;
  const int wm = wave >> 1, wn = wave & 1;

  __shared__ __hip_bfloat16 As[128 * 64];
  __shared__ __hip_bfloat16 Bs[128 * 64];

  f32x4 acc[4][4] = {};
  const int lrow = lane >> 3;
  const int lslot = lane & 7;
  const int scol = (lslot ^ lrow) * 8;
  const size_t abase = (size_t)bm * 128 * K;
  const size_t bbase = (size_t)bn * 128 * K;
  const int r3 = l15 & 7;

  for (int k0 = 0; k0 < K; k0 += 64) {
#pragma unroll
    for (int i = 0; i < 4; ++i) {
      int seg = i * 4 + wave;
      int row = seg * 8 + lrow;
      gload16(A + abase + (size_t)row * K + k0 + scol, &As[seg * 512]);
      gload16(Bt + bbase + (size_t)row * K + k0 + scol, &Bs[seg * 512]);
    }
    __syncthreads();
#pragma unroll
    for (int ks = 0; ks < 2; ++ks) {
      const int slot = (ks * 4 + lg) ^ r3;
      short8 af[4], bf[4];
#pragma unroll
      for (int mi = 0; mi < 4; ++mi)
        af[mi] = *(const short8*)&As[(wm * 64 + mi * 16 + l15) * 64 + slot * 8];
#pragma unroll
      for (int ni = 0; ni < 4; ++ni)
        bf[ni] = *(const short8*)&Bs[(wn * 64 + ni * 16 + l15) * 64 + slot * 8];
#pragma unroll
      for (int mi = 0; mi < 4; ++mi)
#pragma unroll
        for (int ni = 0; ni < 4; ++ni)
          acc[mi][ni] = __builtin_amdgcn_mfma_f32_16x16x32_bf16(af[mi], bf[ni], acc[mi][ni], 0, 0, 0);
    }
    __syncthreads();
  }
#pragma unroll
  for (int mi = 0; mi < 4; ++mi)
#pragma unroll
    for (int ni = 0; ni < 4; ++ni) {
      int row = bm * 128 + wm * 64 + mi * 16 + lg * 4;
      int col = bn * 128 + wn * 64 + ni * 16 + l15;
#pragma unroll
      for (int r = 0; r < 4; ++r)
        C[(size_t)(row + r) * N + col] = acc[mi][ni][r];
    }
}

// ---------------- block-sparse attention (R3-verified staged version) ----------------
__global__ __launch_bounds__(256, 2) void attn_kernel(
    const __hip_bfloat16* __restrict__ Qb,  // [4096][2048]
    const __hip_bfloat16* __restrict__ Kb,  // [4096][512]
    const __hip_bfloat16* __restrict__ Vt,  // [512][4096]  (channel-major)
    const float* __restrict__ amask,        // [4096]
    __hip_bfloat16* __restrict__ AO)        // [4096][2048]
{
  const int bid = blockIdx.x;
  const int h = bid & 15;
  const int bi = bid >> 4;
  const int kvh = h >> 2;
  const int tid = threadIdx.x;
  const int wave = tid >> 6, lane = tid & 63;
  const int l15 = lane & 15, lg = lane >> 4;

  int sel[6]; int nsel = 0;
  {
    int gtop = bi >> 2;
    for (int j = 0; j <= bi; ++j) {
      bool pick = (j == 0) || (j >= bi - 3) || (((j & 3) == 0) && ((j >> 2) >= gtop - 1));
      if (pick && nsel < 6) sel[nsel++] = j;
    }
  }

  __shared__ __hip_bfloat16 kvs[128 * 72];
  __shared__ __hip_bfloat16 Pb[64 * 72];

  short8 qf[4];
  {
    const __hip_bfloat16* qbase =
        Qb + (size_t)(bi * 64 + wave * 16 + l15) * 2048 + h * 128 + lg * 8;
#pragma unroll
    for (int ks = 0; ks < 4; ++ks) qf[ks] = *(const short8*)(qbase + ks * 32);
  }

  f32x4 sc[6][4] = {};
#pragma unroll
  for (int j = 0; j < 6; ++j) {
    if (j < nsel) {
      int kb = sel[j];
#pragma unroll
      for (int i = 0; i < 4; ++i) {
        int e = (i * 256 + tid) * 8;
        int r = e >> 7, c = e & 127;
        short8 v = *(const short8*)(Kb + (size_t)(kb * 64 + r) * 512 + kvh * 128 + c);
        *(short8*)&kvs[r * 136 + c] = v;
      }
      __syncthreads();
#pragma unroll
      for (int nf = 0; nf < 4; ++nf)
#pragma unroll
        for (int ks = 0; ks < 4; ++ks) {
          short8 bfr = *(const short8*)&kvs[(nf * 16 + l15) * 136 + ks * 32 + lg * 8];
          sc[j][nf] = __builtin_amdgcn_mfma_f32_16x16x32_bf16(qf[ks], bfr, sc[j][nf], 0, 0, 0);
        }
      __syncthreads();
    }
  }

  float rowmax[4] = {-3.0e38f, -3.0e38f, -3.0e38f, -3.0e38f};
#pragma unroll
  for (int j = 0; j < 6; ++j) {
    if (j >= nsel) continue;
    int kb = sel[j];
#pragma unroll
    for (int nf = 0; nf < 4; ++nf) {
      int keyg = kb * 64 + nf * 16 + l15;
      float mterm = (1.0f - amask[keyg]) * NEGV;
      int keyl = nf * 16 + l15;
#pragma unroll
      for (int r = 0; r < 4; ++r) {
        float s = sc[j][nf][r] * SCALE + mterm;
        if (kb == bi) {
          int qrow = wave * 16 + lg * 4 + r;
          if (keyl > qrow) s = NEGV;
        }
        sc[j][nf][r] = s;
        rowmax[r] = fmaxf(rowmax[r], s);
      }
    }
  }
#pragma unroll
  for (int r = 0; r < 4; ++r) {
    float v = rowmax[r];
    v = fmaxf(v, __shfl_xor(v, 1)); v = fmaxf(v, __shfl_xor(v, 2));
    v = fmaxf(v, __shfl_xor(v, 4)); v = fmaxf(v, __shfl_xor(v, 8));
    rowmax[r] = v;
  }
  float rinv[4] = {0.f, 0.f, 0.f, 0.f};
#pragma unroll
  for (int j = 0; j < 6; ++j) {
    if (j >= nsel) continue;
#pragma unroll
    for (int nf = 0; nf < 4; ++nf)
#pragma unroll
      for (int r = 0; r < 4; ++r) {
        float p = __expf(sc[j][nf][r] - rowmax[r]);
        sc[j][nf][r] = p;
        rinv[r] += p;
      }
  }
#pragma unroll
  for (int r = 0; r < 4; ++r) {
    float v = rinv[r];
    v += __shfl_xor(v, 1); v += __shfl_xor(v, 2);
    v += __shfl_xor(v, 4); v += __shfl_xor(v, 8);
    rinv[r] = 1.0f / v;
  }

  f32x4 oacc[8] = {};
#pragma unroll
  for (int j = 0; j < 6; ++j) {
    if (j < nsel) {
      int kb = sel[j];
#pragma unroll
      for (int nf = 0; nf < 4; ++nf)
#pragma unroll
        for (int r = 0; r < 4; ++r) {
          int qrow = wave * 16 + lg * 4 + r;
          Pb[qrow * 72 + nf * 16 + l15] = __float2bfloat16(sc[j][nf][r] * rinv[r]);
        }
#pragma unroll
      for (int i = 0; i < 4; ++i) {
        int e = (i * 256 + tid) * 8;
        int d = e >> 6, c = e & 63;
        short8 v = *(const short8*)(Vt + (size_t)(kvh * 128 + d) * 4096 + kb * 64 + c);
        *(short8*)&kvs[d * 72 + c] = v;
      }
      __syncthreads();
#pragma unroll
      for (int ks = 0; ks < 2; ++ks) {
        short8 pa = *(const short8*)&Pb[(wave * 16 + l15) * 72 + ks * 32 + lg * 8];
#pragma unroll
        for (int df = 0; df < 8; ++df) {
          short8 vb = *(const short8*)&kvs[(df * 16 + l15) * 72 + ks * 32 + lg * 8];
          oacc[df] = __builtin_amdgcn_mfma_f32_16x16x32_bf16(pa, vb, oacc[df], 0, 0, 0);
        }
      }
      __syncthreads();
    }
  }

#pragma unroll
  for (int df = 0; df < 8; ++df)
#pragma unroll
    for (int r = 0; r < 4; ++r) {
      int qrow = bi * 64 + wave * 16 + lg * 4 + r;
      AO[(size_t)qrow * 2048 + h * 128 + df * 16 + l15] = __float2bfloat16(oacc[df][r]);
    }
}

// ---------------- launch ----------------
extern "C" void kernel_launch(void* const* d_in, const int* in_sizes, int n_in,
                              void* d_out, int out_size, void* d_ws, size_t ws_size,
                              hipStream_t stream) {
  const float* hidden = (const float*)d_in[0];
  const float* cosb   = (const float*)d_in[1];
  const float* sinb   = (const float*)d_in[2];
  const float* Wq     = (const float*)d_in[3];
  const float* Wk     = (const float*)d_in[4];
  const float* Wv     = (const float*)d_in[5];
  const float* Wo     = (const float*)d_in[6];
  const float* amask  = (const float*)d_in[7];

  char* ws = (char*)d_ws;
  __hip_bfloat16* Xb   = (__hip_bfloat16*)(ws);               // 16,777,216 B  [4096][2048]
  __hip_bfloat16* Wt   = (__hip_bfloat16*)(ws + 16777216);    // 12,582,912 B  [3072][2048]
  __hip_bfloat16* Wot  = (__hip_bfloat16*)(ws + 29360128);    //  8,388,608 B  [2048][2048]
  __hip_bfloat16* Qb   = (__hip_bfloat16*)(ws + 37748736);    // 16,777,216 B  [4096][2048]
  __hip_bfloat16* Kb   = (__hip_bfloat16*)(ws + 54525952);    //  4,194,304 B  [4096][512]
  __hip_bfloat16* Vb   = (__hip_bfloat16*)(ws + 58720256);    //  4,194,304 B  [4096][512]
  __hip_bfloat16* Vt   = (__hip_bfloat16*)(ws + 62914560);    //  4,194,304 B  [512][4096]
  __hip_bfloat16* AO   = Xb;  // Xb dead after gemm_qkv8p; reuse for attention output

  conv_hidden<<<8192, 256, 0, stream>>>(hidden, Xb);
  transpose_f32_to_bf16<<<dim3(32, 32), 256, 0, stream>>>(Wq, Wt, 2048, 2048);
  transpose_f32_to_bf16<<<dim3(32, 8),  256, 0, stream>>>(Wk, Wt + (size_t)2048 * 2048, 2048, 512);
  transpose_f32_to_bf16<<<dim3(32, 8),  256, 0, stream>>>(Wv, Wt + (size_t)2560 * 2048, 2048, 512);
  transpose_f32_to_bf16<<<dim3(32, 32), 256, 0, stream>>>(Wo, Wot, 2048, 2048);

  gemm_qkv8p<<<dim3(16, 12), 512, 0, stream>>>(Xb, Wt, Qb, Kb, Vb);

  rope_inplace<<<1280, 256, 0, stream>>>(cosb, sinb, Qb, Kb);
  transpose_v<<<dim3(64, 8), 256, 0, stream>>>(Vb, Vt);

  attn_kernel<<<1024, 256, 0, stream>>>(Qb, Kb, Vt, amask, AO);

  gemm_bt<<<dim3(32, 16), 256, 0, stream>>>(AO, Wot, (float*)d_out, 4096, 2048, 2048);
}

// Round 9
// 169.051 us; speedup vs baseline: 1.0456x; 1.0456x over previous
//
#include <hip/hip_runtime.h>
#include <hip/hip_bf16.h>

// HumanVAttention: QKV proj -> in-place RoPE -> V transpose -> GQA block-sparse attn -> out proj
// B=1 S=4096 HID=2048 NH=16 NKV=4 HD=128 BLK=64 LOCAL=4 GNB=2 STRIDE=4 ROT=64

typedef short short8 __attribute__((ext_vector_type(8)));
typedef float f32x4  __attribute__((ext_vector_type(4)));

#define NEGV   (-1.0e9f)
#define SCALE  (0.08838834764831845f)

__device__ __forceinline__ void gload16(const void* g, void* l) {
  __builtin_amdgcn_global_load_lds(
      (const __attribute__((address_space(1))) unsigned int*)g,
      (__attribute__((address_space(3))) unsigned int*)l, 16, 0, 0);
}

__device__ __forceinline__ float bf2f(short s) {
  union { unsigned u; float f; } c;
  c.u = ((unsigned)(unsigned short)s) << 16;
  return c.f;
}

__device__ __forceinline__ short f2bf_s(float f) {
  __hip_bfloat16 b = __float2bfloat16(f);
  short s;
  __builtin_memcpy(&s, &b, 2);
  return s;
}

// ---------------- fused prep: hidden f32->bf16 convert + 4 weight transposes ----------------
// grid 10752 x 256:
//   b in [0,8192):      conv_hidden  (one float4/thread)
//   [8192,9216):        Wq  2048x2048 -> Wt[0..]
//   [9216,9472):        Wk  2048x512  -> Wt+2048*2048
//   [9472,9728):        Wv  2048x512  -> Wt+2560*2048
//   [9728,10752):       Wo  2048x2048 -> Wot
__global__ void prep_all(const float* __restrict__ H, const float* __restrict__ Wq,
                         const float* __restrict__ Wk, const float* __restrict__ Wv,
                         const float* __restrict__ Wo, __hip_bfloat16* __restrict__ X,
                         __hip_bfloat16* __restrict__ Wt, __hip_bfloat16* __restrict__ Wot) {
  __shared__ __hip_bfloat16 tile[64][73];
  int b = blockIdx.x;
  if (b < 8192) {
    size_t t = (size_t)b * 256 + threadIdx.x;
    float4 v = *(const float4*)(H + t * 4);
    __hip_bfloat16* o = X + t * 4;
    o[0] = __float2bfloat16(v.x); o[1] = __float2bfloat16(v.y);
    o[2] = __float2bfloat16(v.z); o[3] = __float2bfloat16(v.w);
    return;
  }
  const float* src; __hip_bfloat16* dst; int C; int idx;
  if (b < 9216)      { src = Wq; dst = Wt;                          C = 2048; idx = b - 8192; }
  else if (b < 9472) { src = Wk; dst = Wt + (size_t)2048 * 2048;    C = 512;  idx = b - 9216; }
  else if (b < 9728) { src = Wv; dst = Wt + (size_t)2560 * 2048;    C = 512;  idx = b - 9472; }
  else               { src = Wo; dst = Wot;                         C = 2048; idx = b - 9728; }
  int r0 = (idx & 31) * 64, c0 = (idx >> 5) * 64;
  int c = threadIdx.x & 63, rq = threadIdx.x >> 6;
#pragma unroll
  for (int i = 0; i < 16; ++i) {
    int r = i * 4 + rq;
    tile[r][c] = __float2bfloat16(src[(size_t)(r0 + r) * C + c0 + c]);
  }
  __syncthreads();
#pragma unroll
  for (int i = 0; i < 16; ++i) {
    int cc = i * 4 + rq;
    dst[(size_t)(c0 + cc) * 2048 + r0 + c] = tile[c][cc];
  }
}

// ---------------- V transpose: Vb[s][c] (bf16, [4096][512]) -> Vt[c][s] ----------------
__global__ void transpose_v(const __hip_bfloat16* __restrict__ Vb,
                            __hip_bfloat16* __restrict__ Vt) {
  __shared__ __hip_bfloat16 tile[64][73];
  int s0 = blockIdx.x * 64, c0 = blockIdx.y * 64;
  int c = threadIdx.x & 63, rq = threadIdx.x >> 6;
#pragma unroll
  for (int i = 0; i < 16; ++i) {
    int r = i * 4 + rq;
    tile[r][c] = Vb[(size_t)(s0 + r) * 512 + c0 + c];
  }
  __syncthreads();
#pragma unroll
  for (int i = 0; i < 16; ++i) {
    int cc = i * 4 + rq;
    Vt[(size_t)(c0 + cc) * 4096 + s0 + c] = tile[c][cc];
  }
}

// ---------------- in-place partial RoPE on Qb and Kb (verified R6) ----------------
__global__ void rope_inplace(const float* __restrict__ cosb, const float* __restrict__ sinb,
                             __hip_bfloat16* __restrict__ Qb, __hip_bfloat16* __restrict__ Kb) {
  int t = blockIdx.x * 256 + threadIdx.x;
  __hip_bfloat16* p;
  int s;
  if (t < 262144) {               // Q: s = t>>6, then 16 h x 4 g
    s = t >> 6;
    int rem = t & 63;
    p = Qb + (size_t)s * 2048 + (rem >> 2) * 128 + (rem & 3) * 8;
  } else {                        // K: s = tk>>4, then 4 h x 4 g
    int tk = t - 262144;
    s = tk >> 4;
    int rem = tk & 15;
    p = Kb + (size_t)s * 512 + (rem >> 2) * 128 + (rem & 3) * 8;
  }
  const int g8 = (t & 3) * 8;     // d offset in [0,32)
  const float* cp = cosb + (size_t)s * 64 + g8;
  const float* sp = sinb + (size_t)s * 64 + g8;
  short8 a = *(const short8*)p;          // x[d],    d in [0,32)
  short8 b = *(const short8*)(p + 32);   // x[d+32]
  float ca[8], sa[8], cb[8], sb[8];
  *(float4*)&ca[0] = *(const float4*)cp;        *(float4*)&ca[4] = *(const float4*)(cp + 4);
  *(float4*)&cb[0] = *(const float4*)(cp + 32); *(float4*)&cb[4] = *(const float4*)(cp + 36);
  *(float4*)&sa[0] = *(const float4*)sp;        *(float4*)&sa[4] = *(const float4*)(sp + 4);
  *(float4*)&sb[0] = *(const float4*)(sp + 32); *(float4*)&sb[4] = *(const float4*)(sp + 36);
  short8 oa, ob;
#pragma unroll
  for (int i = 0; i < 8; ++i) {
    float av = bf2f(a[i]), bv = bf2f(b[i]);
    oa[i] = f2bf_s(av * ca[i] - bv * sa[i]);   // rot_half: d<32 -> -x[d+32]
    ob[i] = f2bf_s(bv * cb[i] + av * sb[i]);   // d>=32   -> +x[d-32]
  }
  *(short8*)p = oa;
  *(short8*)(p + 32) = ob;
}

// ---------------- GEMM1: 256x256 tile, pipelined 4-phase (MFMA-first, reads-under-MFMA) ----
// X[4096][2048] . Wt[3072][2048]^T -> Qb/Kb/Vb. 8 waves (2M x 4N), per-wave C 128x64.
// LDS 128 KiB = 2 buf x {A0,A1,B0,B1} half-tiles (128x64 bf16 = 16 KiB each).
// Phase q: [stage; (vmcnt@q3); barrier; 16 MFMA (operands pre-loaded last phase);
//           ds_read next phase's fragments (fly under MFMA pipe drain); lgkmcnt(0)].
// One barrier/phase. vmcnt(4) once per tile (B(t+2) stays in flight - never drains mid-loop).
// Safety: every wave drains its ds_reads (lgkm 0) before its next barrier arrival, and all
// LDS writers sit >=1 barrier after the matching readers' drain point (hand-verified).
__global__ __launch_bounds__(512, 2) void gemm_qkv4p(
    const __hip_bfloat16* __restrict__ A, const __hip_bfloat16* __restrict__ Bt,
    __hip_bfloat16* __restrict__ Qb, __hip_bfloat16* __restrict__ Kb,
    __hip_bfloat16* __restrict__ Vb) {
  const int K = 2048;
  const int tid = threadIdx.x;
  const int wave = tid >> 6, lane = tid & 63;
  const int l15 = lane & 15, lg = lane >> 4;
  const int bm = blockIdx.x, bn = blockIdx.y;
  const int wm = wave >> 2, wn = wave & 3;      // 2M x 4N

  __shared__ __hip_bfloat16 lds[65536];         // 128 KiB

  f32x4 acc[8][4] = {};
  const int srow = lane >> 3;
  const int sslot = lane & 7;
  const int scol = (sslot ^ srow) * 8;          // pre-swizzled global col
  const size_t abase = (size_t)bm * 256 * K;
  const size_t bbase = (size_t)bn * 256 * K;
  const int r3 = l15 & 7;

#define STAGE_HALF(SRC, SBASE, HALF, KO, LBASE)                                  \
  {                                                                              \
    _Pragma("unroll")                                                            \
    for (int l = 0; l < 2; ++l) {                                                \
      int chunk = l * 8 + wave;                                                  \
      int row = chunk * 8 + srow;                                                \
      gload16(SRC + (SBASE) + (size_t)((HALF) * 128 + row) * K + (KO) + scol,    \
              &lds[(LBASE) + chunk * 512]);                                      \
    }                                                                            \
  }

  short8 bfr[4][2];        // B fragments for the whole tile (wave's 64-col strip)
  short8 af[2][2][2];      // [parity][m2][ks] A fragments, double-buffered by phase parity

#define READ_AF(P, Q, BA)                                                        \
  {                                                                              \
    _Pragma("unroll")                                                            \
    for (int m2 = 0; m2 < 2; ++m2)                                               \
      _Pragma("unroll")                                                          \
      for (int ks = 0; ks < 2; ++ks) {                                           \
        int row = ((Q) * 2 + m2) * 16 + l15;                                     \
        int slot = (ks * 4 + lg) ^ r3;                                           \
        af[P][m2][ks] = *(const short8*)&lds[(BA) + row * 64 + slot * 8];        \
      }                                                                          \
  }

#define READ_BF(BB)                                                              \
  {                                                                              \
    _Pragma("unroll")                                                            \
    for (int ni = 0; ni < 4; ++ni)                                               \
      _Pragma("unroll")                                                          \
      for (int ks = 0; ks < 2; ++ks) {                                           \
        int row = (wn & 1) * 64 + ni * 16 + l15;                                 \
        int slot = (ks * 4 + lg) ^ r3;                                           \
        bfr[ni][ks] = *(const short8*)&lds[(BB) + row * 64 + slot * 8];          \
      }                                                                          \
  }

#define MFMA_Q(Q, P)                                                             \
  {                                                                              \
    __builtin_amdgcn_s_setprio(1);                                               \
    _Pragma("unroll")                                                            \
    for (int ks = 0; ks < 2; ++ks)                                               \
      _Pragma("unroll")                                                          \
      for (int m2 = 0; m2 < 2; ++m2)                                             \
        _Pragma("unroll")                                                        \
        for (int ni = 0; ni < 4; ++ni)                                           \
          acc[(Q) * 2 + m2][ni] = __builtin_amdgcn_mfma_f32_16x16x32_bf16(       \
              af[P][m2][ks], bfr[ni][ks], acc[(Q) * 2 + m2][ni], 0, 0, 0);       \
    __builtin_amdgcn_s_setprio(0);                                               \
  }

#define LGKM0()                                                                  \
  asm volatile("s_waitcnt lgkmcnt(0)" ::: "memory");                             \
  __builtin_amdgcn_sched_barrier(0);

  // ---- prologue: B0(0),B1(0),A0(0),A1(0),B0(1),B1(1); preload bfr(0)+af0(0) ----
  STAGE_HALF(Bt, bbase, 0, 0, 16384);
  STAGE_HALF(Bt, bbase, 1, 0, 24576);
  STAGE_HALF(A, abase, 0, 0, 0);
  STAGE_HALF(A, abase, 1, 0, 8192);
  STAGE_HALF(Bt, bbase, 0, 64, 49152);
  STAGE_HALF(Bt, bbase, 1, 64, 57344);
  asm volatile("s_waitcnt vmcnt(4)" ::: "memory");
  __builtin_amdgcn_sched_barrier(0);
  __builtin_amdgcn_s_barrier();
  {
    const int bA0 = wm * 8192;
    const int bB0 = 16384 + (wn >> 1) * 8192;
    READ_BF(bB0);
    READ_AF(0, 0, bA0);
  }
  LGKM0();

  for (int t = 0; t < 32; ++t) {
    const int buf = (t & 1) * 32768;
    const int nbuf = buf ^ 32768;
    const int bA = buf + wm * 8192;
    // ---- q0: MFMA(af[0]); read af[1]=q1 ----
    if (t + 1 < 32) STAGE_HALF(A, abase, 0, (t + 1) * 64, nbuf);
    __builtin_amdgcn_s_barrier();
    MFMA_Q(0, 0);
    READ_AF(1, 1, bA);
    LGKM0();
    // ---- q1 ----
    if (t + 1 < 32) STAGE_HALF(A, abase, 1, (t + 1) * 64, nbuf + 8192);
    __builtin_amdgcn_s_barrier();
    MFMA_Q(1, 1);
    READ_AF(0, 2, bA);
    LGKM0();
    // ---- q2 ----
    if (t + 2 < 32) STAGE_HALF(Bt, bbase, 0, (t + 2) * 64, buf + 16384);
    __builtin_amdgcn_s_barrier();
    MFMA_Q(2, 0);
    READ_AF(1, 3, bA);
    LGKM0();
    // ---- q3: counted vmcnt; MFMA; then preload next tile's bfr + af0 ----
    if (t + 2 < 32) STAGE_HALF(Bt, bbase, 1, (t + 2) * 64, buf + 24576);
    if (t < 30) asm volatile("s_waitcnt vmcnt(4)" ::: "memory");
    else        asm volatile("s_waitcnt vmcnt(0)" ::: "memory");
    __builtin_amdgcn_sched_barrier(0);
    __builtin_amdgcn_s_barrier();
    MFMA_Q(3, 1);
    if (t + 1 < 32) {
      const int nbA = nbuf + wm * 8192;
      const int nbB = nbuf + 16384 + (wn >> 1) * 8192;
      READ_BF(nbB);
      READ_AF(0, 0, nbA);
    }
    LGKM0();
  }
#undef STAGE_HALF
#undef READ_AF
#undef READ_BF
#undef MFMA_Q
#undef LGKM0

  // ---- epilogue: bn tile (256 cols) maps wholly to Q (bn<8), K (8,9) or V (10,11) ----
  __hip_bfloat16* dst; int ldc, coff;
  if (bn < 8)       { dst = Qb; ldc = 2048; coff = bn * 256; }
  else if (bn < 10) { dst = Kb; ldc = 512;  coff = bn * 256 - 2048; }
  else              { dst = Vb; ldc = 512;  coff = bn * 256 - 2560; }
#pragma unroll
  for (int m8 = 0; m8 < 8; ++m8)
#pragma unroll
    for (int ni = 0; ni < 4; ++ni) {
      int row = bm * 256 + wm * 128 + m8 * 16 + lg * 4;
      int col = coff + wn * 64 + ni * 16 + l15;
#pragma unroll
      for (int r = 0; r < 4; ++r)
        dst[(size_t)(row + r) * ldc + col] = __float2bfloat16(acc[m8][ni][r]);
    }
}

// ---------------- GEMM2: C[M][N] f32 = A[M][K] bf16 . Bt[N][K]^T bf16 (verified 128^2) ----------------
__global__ __launch_bounds__(256) void gemm_bt(
    const __hip_bfloat16* __restrict__ A, const __hip_bfloat16* __restrict__ Bt,
    float* __restrict__ C, int M, int N, int K) {
  const int tid = threadIdx.x;
  const int wave = tid >> 6, lane = tid & 63;
  const int l15 = lane & 15, lg = lane >> 4;
  const int bm = blockIdx.x, bn = blockIdx.y;
  const int wm = wave >> 1, wn = wave & 1;

  __shared__ __hip_bfloat16 As[128 * 64];
  __shared__ __hip_bfloat16 Bs[128 * 64];

  f32x4 acc[4][4] = {};
  const int lrow = lane >> 3;
  const int lslot = lane & 7;
  const int scol = (lslot ^ lrow) * 8;
  const size_t abase = (size_t)bm * 128 * K;
  const size_t bbase = (size_t)bn * 128 * K;
  const int r3 = l15 & 7;

  for (int k0 = 0; k0 < K; k0 += 64) {
#pragma unroll
    for (int i = 0; i < 4; ++i) {
      int seg = i * 4 + wave;
      int row = seg * 8 + lrow;
      gload16(A + abase + (size_t)row * K + k0 + scol, &As[seg * 512]);
      gload16(Bt + bbase + (size_t)row * K + k0 + scol, &Bs[seg * 512]);
    }
    __syncthreads();
#pragma unroll
    for (int ks = 0; ks < 2; ++ks) {
      const int slot = (ks * 4 + lg) ^ r3;
      short8 af[4], bf[4];
#pragma unroll
      for (int mi = 0; mi < 4; ++mi)
        af[mi] = *(const short8*)&As[(wm * 64 + mi * 16 + l15) * 64 + slot * 8];
#pragma unroll
      for (int ni = 0; ni < 4; ++ni)
        bf[ni] = *(const short8*)&Bs[(wn * 64 + ni * 16 + l15) * 64 + slot * 8];
#pragma unroll
      for (int mi = 0; mi < 4; ++mi)
#pragma unroll
        for (int ni = 0; ni < 4; ++ni)
          acc[mi][ni] = __builtin_amdgcn_mfma_f32_16x16x32_bf16(af[mi], bf[ni], acc[mi][ni], 0, 0, 0);
    }
    __syncthreads();
  }
#pragma unroll
  for (int mi = 0; mi < 4; ++mi)
#pragma unroll
    for (int ni = 0; ni < 4; ++ni) {
      int row = bm * 128 + wm * 64 + mi * 16 + lg * 4;
      int col = bn * 128 + wn * 64 + ni * 16 + l15;
#pragma unroll
      for (int r = 0; r < 4; ++r)
        C[(size_t)(row + r) * N + col] = acc[mi][ni][r];
    }
}

// ---------------- block-sparse attention (R3-verified staged version) ----------------
__global__ __launch_bounds__(256, 2) void attn_kernel(
    const __hip_bfloat16* __restrict__ Qb,  // [4096][2048]
    const __hip_bfloat16* __restrict__ Kb,  // [4096][512]
    const __hip_bfloat16* __restrict__ Vt,  // [512][4096]  (channel-major)
    const float* __restrict__ amask,        // [4096]
    __hip_bfloat16* __restrict__ AO)        // [4096][2048]
{
  const int bid = blockIdx.x;
  const int h = bid & 15;
  const int bi = bid >> 4;
  const int kvh = h >> 2;
  const int tid = threadIdx.x;
  const int wave = tid >> 6, lane = tid & 63;
  const int l15 = lane & 15, lg = lane >> 4;

  int sel[6]; int nsel = 0;
  {
    int gtop = bi >> 2;
    for (int j = 0; j <= bi; ++j) {
      bool pick = (j == 0) || (j >= bi - 3) || (((j & 3) == 0) && ((j >> 2) >= gtop - 1));
      if (pick && nsel < 6) sel[nsel++] = j;
    }
  }

  __shared__ __hip_bfloat16 kvs[128 * 72];
  __shared__ __hip_bfloat16 Pb[64 * 72];

  short8 qf[4];
  {
    const __hip_bfloat16* qbase =
        Qb + (size_t)(bi * 64 + wave * 16 + l15) * 2048 + h * 128 + lg * 8;
#pragma unroll
    for (int ks = 0; ks < 4; ++ks) qf[ks] = *(const short8*)(qbase + ks * 32);
  }

  f32x4 sc[6][4] = {};
#pragma unroll
  for (int j = 0; j < 6; ++j) {
    if (j < nsel) {
      int kb = sel[j];
#pragma unroll
      for (int i = 0; i < 4; ++i) {
        int e = (i * 256 + tid) * 8;
        int r = e >> 7, c = e & 127;
        short8 v = *(const short8*)(Kb + (size_t)(kb * 64 + r) * 512 + kvh * 128 + c);
        *(short8*)&kvs[r * 136 + c] = v;
      }
      __syncthreads();
#pragma unroll
      for (int nf = 0; nf < 4; ++nf)
#pragma unroll
        for (int ks = 0; ks < 4; ++ks) {
          short8 bfr = *(const short8*)&kvs[(nf * 16 + l15) * 136 + ks * 32 + lg * 8];
          sc[j][nf] = __builtin_amdgcn_mfma_f32_16x16x32_bf16(qf[ks], bfr, sc[j][nf], 0, 0, 0);
        }
      __syncthreads();
    }
  }

  float rowmax[4] = {-3.0e38f, -3.0e38f, -3.0e38f, -3.0e38f};
#pragma unroll
  for (int j = 0; j < 6; ++j) {
    if (j >= nsel) continue;
    int kb = sel[j];
#pragma unroll
    for (int nf = 0; nf < 4; ++nf) {
      int keyg = kb * 64 + nf * 16 + l15;
      float mterm = (1.0f - amask[keyg]) * NEGV;
      int keyl = nf * 16 + l15;
#pragma unroll
      for (int r = 0; r < 4; ++r) {
        float s = sc[j][nf][r] * SCALE + mterm;
        if (kb == bi) {
          int qrow = wave * 16 + lg * 4 + r;
          if (keyl > qrow) s = NEGV;
        }
        sc[j][nf][r] = s;
        rowmax[r] = fmaxf(rowmax[r], s);
      }
    }
  }
#pragma unroll
  for (int r = 0; r < 4; ++r) {
    float v = rowmax[r];
    v = fmaxf(v, __shfl_xor(v, 1)); v = fmaxf(v, __shfl_xor(v, 2));
    v = fmaxf(v, __shfl_xor(v, 4)); v = fmaxf(v, __shfl_xor(v, 8));
    rowmax[r] = v;
  }
  float rinv[4] = {0.f, 0.f, 0.f, 0.f};
#pragma unroll
  for (int j = 0; j < 6; ++j) {
    if (j >= nsel) continue;
#pragma unroll
    for (int nf = 0; nf < 4; ++nf)
#pragma unroll
      for (int r = 0; r < 4; ++r) {
        float p = __expf(sc[j][nf][r] - rowmax[r]);
        sc[j][nf][r] = p;
        rinv[r] += p;
      }
  }
#pragma unroll
  for (int r = 0; r < 4; ++r) {
    float v = rinv[r];
    v += __shfl_xor(v, 1); v += __shfl_xor(v, 2);
    v += __shfl_xor(v, 4); v += __shfl_xor(v, 8);
    rinv[r] = 1.0f / v;
  }

  f32x4 oacc[8] = {};
#pragma unroll
  for (int j = 0; j < 6; ++j) {
    if (j < nsel) {
      int kb = sel[j];
#pragma unroll
      for (int nf = 0; nf < 4; ++nf)
#pragma unroll
        for (int r = 0; r < 4; ++r) {
          int qrow = wave * 16 + lg * 4 + r;
          Pb[qrow * 72 + nf * 16 + l15] = __float2bfloat16(sc[j][nf][r] * rinv[r]);
        }
#pragma unroll
      for (int i = 0; i < 4; ++i) {
        int e = (i * 256 + tid) * 8;
        int d = e >> 6, c = e & 63;
        short8 v = *(const short8*)(Vt + (size_t)(kvh * 128 + d) * 4096 + kb * 64 + c);
        *(short8*)&kvs[d * 72 + c] = v;
      }
      __syncthreads();
#pragma unroll
      for (int ks = 0; ks < 2; ++ks) {
        short8 pa = *(const short8*)&Pb[(wave * 16 + l15) * 72 + ks * 32 + lg * 8];
#pragma unroll
        for (int df = 0; df < 8; ++df) {
          short8 vb = *(const short8*)&kvs[(df * 16 + l15) * 72 + ks * 32 + lg * 8];
          oacc[df] = __builtin_amdgcn_mfma_f32_16x16x32_bf16(pa, vb, oacc[df], 0, 0, 0);
        }
      }
      __syncthreads();
    }
  }

#pragma unroll
  for (int df = 0; df < 8; ++df)
#pragma unroll
    for (int r = 0; r < 4; ++r) {
      int qrow = bi * 64 + wave * 16 + lg * 4 + r;
      AO[(size_t)qrow * 2048 + h * 128 + df * 16 + l15] = __float2bfloat16(oacc[df][r]);
    }
}

// ---------------- launch ----------------
extern "C" void kernel_launch(void* const* d_in, const int* in_sizes, int n_in,
                              void* d_out, int out_size, void* d_ws, size_t ws_size,
                              hipStream_t stream) {
  const float* hidden = (const float*)d_in[0];
  const float* cosb   = (const float*)d_in[1];
  const float* sinb   = (const float*)d_in[2];
  const float* Wq     = (const float*)d_in[3];
  const float* Wk     = (const float*)d_in[4];
  const float* Wv     = (const float*)d_in[5];
  const float* Wo     = (const float*)d_in[6];
  const float* amask  = (const float*)d_in[7];

  char* ws = (char*)d_ws;
  __hip_bfloat16* Xb   = (__hip_bfloat16*)(ws);               // 16,777,216 B  [4096][2048]
  __hip_bfloat16* Wt   = (__hip_bfloat16*)(ws + 16777216);    // 12,582,912 B  [3072][2048]
  __hip_bfloat16* Wot  = (__hip_bfloat16*)(ws + 29360128);    //  8,388,608 B  [2048][2048]
  __hip_bfloat16* Qb   = (__hip_bfloat16*)(ws + 37748736);    // 16,777,216 B  [4096][2048]
  __hip_bfloat16* Kb   = (__hip_bfloat16*)(ws + 54525952);    //  4,194,304 B  [4096][512]
  __hip_bfloat16* Vb   = (__hip_bfloat16*)(ws + 58720256);    //  4,194,304 B  [4096][512]
  __hip_bfloat16* Vt   = (__hip_bfloat16*)(ws + 62914560);    //  4,194,304 B  [512][4096]
  __hip_bfloat16* AO   = Xb;  // Xb dead after gemm_qkv4p; reuse for attention output

  prep_all<<<10752, 256, 0, stream>>>(hidden, Wq, Wk, Wv, Wo, Xb, Wt, Wot);

  gemm_qkv4p<<<dim3(16, 12), 512, 0, stream>>>(Xb, Wt, Qb, Kb, Vb);

  rope_inplace<<<1280, 256, 0, stream>>>(cosb, sinb, Qb, Kb);
  transpose_v<<<dim3(64, 8), 256, 0, stream>>>(Vb, Vt);

  attn_kernel<<<1024, 256, 0, stream>>>(Qb, Kb, Vt, amask, AO);

  gemm_bt<<<dim3(32, 16), 256, 0, stream>>>(AO, Wot, (float*)d_out, 4096, 2048, 2048);
}

// Round 10
// 165.532 us; speedup vs baseline: 1.0678x; 1.0213x over previous
//
#include <hip/hip_runtime.h>
#include <hip/hip_bf16.h>

// HumanVAttention: QKV proj -> in-place RoPE + V transpose -> GQA block-sparse attn -> out proj
// B=1 S=4096 HID=2048 NH=16 NKV=4 HD=128 BLK=64 LOCAL=4 GNB=2 STRIDE=4 ROT=64

typedef short short8 __attribute__((ext_vector_type(8)));
typedef float f32x4  __attribute__((ext_vector_type(4)));

#define NEGV   (-1.0e9f)
#define SCALE  (0.08838834764831845f)

__device__ __forceinline__ void gload16(const void* g, void* l) {
  __builtin_amdgcn_global_load_lds(
      (const __attribute__((address_space(1))) unsigned int*)g,
      (__attribute__((address_space(3))) unsigned int*)l, 16, 0, 0);
}

__device__ __forceinline__ float bf2f(short s) {
  union { unsigned u; float f; } c;
  c.u = ((unsigned)(unsigned short)s) << 16;
  return c.f;
}

__device__ __forceinline__ short f2bf_s(float f) {
  __hip_bfloat16 b = __float2bfloat16(f);
  short s;
  __builtin_memcpy(&s, &b, 2);
  return s;
}

// ---------------- fused prep: hidden f32->bf16 convert + 4 weight transposes ----------------
__global__ void prep_all(const float* __restrict__ H, const float* __restrict__ Wq,
                         const float* __restrict__ Wk, const float* __restrict__ Wv,
                         const float* __restrict__ Wo, __hip_bfloat16* __restrict__ X,
                         __hip_bfloat16* __restrict__ Wt, __hip_bfloat16* __restrict__ Wot) {
  __shared__ __hip_bfloat16 tile[64][73];
  int b = blockIdx.x;
  if (b < 8192) {
    size_t t = (size_t)b * 256 + threadIdx.x;
    float4 v = *(const float4*)(H + t * 4);
    __hip_bfloat16* o = X + t * 4;
    o[0] = __float2bfloat16(v.x); o[1] = __float2bfloat16(v.y);
    o[2] = __float2bfloat16(v.z); o[3] = __float2bfloat16(v.w);
    return;
  }
  const float* src; __hip_bfloat16* dst; int C; int idx;
  if (b < 9216)      { src = Wq; dst = Wt;                          C = 2048; idx = b - 8192; }
  else if (b < 9472) { src = Wk; dst = Wt + (size_t)2048 * 2048;    C = 512;  idx = b - 9216; }
  else if (b < 9728) { src = Wv; dst = Wt + (size_t)2560 * 2048;    C = 512;  idx = b - 9472; }
  else               { src = Wo; dst = Wot;                         C = 2048; idx = b - 9728; }
  int r0 = (idx & 31) * 64, c0 = (idx >> 5) * 64;
  int c = threadIdx.x & 63, rq = threadIdx.x >> 6;
#pragma unroll
  for (int i = 0; i < 16; ++i) {
    int r = i * 4 + rq;
    tile[r][c] = __float2bfloat16(src[(size_t)(r0 + r) * C + c0 + c]);
  }
  __syncthreads();
#pragma unroll
  for (int i = 0; i < 16; ++i) {
    int cc = i * 4 + rq;
    dst[(size_t)(c0 + cc) * 2048 + r0 + c] = tile[c][cc];
  }
}

// ---------------- fused postproc: in-place RoPE (Q,K) + V transpose ----------------
// blocks [0,1280): rope; [1280,1792): transpose Vb[4096][512] -> Vt[512][4096]
__global__ void postproc(const float* __restrict__ cosb, const float* __restrict__ sinb,
                         __hip_bfloat16* __restrict__ Qb, __hip_bfloat16* __restrict__ Kb,
                         const __hip_bfloat16* __restrict__ Vb, __hip_bfloat16* __restrict__ Vt) {
  __shared__ __hip_bfloat16 tile[64][73];
  int blk = blockIdx.x;
  if (blk < 1280) {
    int t = blk * 256 + threadIdx.x;
    __hip_bfloat16* p;
    int s;
    if (t < 262144) {               // Q
      s = t >> 6;
      int rem = t & 63;
      p = Qb + (size_t)s * 2048 + (rem >> 2) * 128 + (rem & 3) * 8;
    } else {                        // K
      int tk = t - 262144;
      s = tk >> 4;
      int rem = tk & 15;
      p = Kb + (size_t)s * 512 + (rem >> 2) * 128 + (rem & 3) * 8;
    }
    const int g8 = (t & 3) * 8;
    const float* cp = cosb + (size_t)s * 64 + g8;
    const float* sp = sinb + (size_t)s * 64 + g8;
    short8 a = *(const short8*)p;
    short8 b = *(const short8*)(p + 32);
    float ca[8], sa[8], cb[8], sb[8];
    *(float4*)&ca[0] = *(const float4*)cp;        *(float4*)&ca[4] = *(const float4*)(cp + 4);
    *(float4*)&cb[0] = *(const float4*)(cp + 32); *(float4*)&cb[4] = *(const float4*)(cp + 36);
    *(float4*)&sa[0] = *(const float4*)sp;        *(float4*)&sa[4] = *(const float4*)(sp + 4);
    *(float4*)&sb[0] = *(const float4*)(sp + 32); *(float4*)&sb[4] = *(const float4*)(sp + 36);
    short8 oa, ob;
#pragma unroll
    for (int i = 0; i < 8; ++i) {
      float av = bf2f(a[i]), bv = bf2f(b[i]);
      oa[i] = f2bf_s(av * ca[i] - bv * sa[i]);
      ob[i] = f2bf_s(bv * cb[i] + av * sb[i]);
    }
    *(short8*)p = oa;
    *(short8*)(p + 32) = ob;
    return;
  }
  int idx = blk - 1280;                     // 512 blocks: 64 x 8
  int s0 = (idx & 63) * 64, c0 = (idx >> 6) * 64;
  int c = threadIdx.x & 63, rq = threadIdx.x >> 6;
#pragma unroll
  for (int i = 0; i < 16; ++i) {
    int r = i * 4 + rq;
    tile[r][c] = Vb[(size_t)(s0 + r) * 512 + c0 + c];
  }
  __syncthreads();
#pragma unroll
  for (int i = 0; i < 16; ++i) {
    int cc = i * 4 + rq;
    Vt[(size_t)(c0 + cc) * 4096 + s0 + c] = tile[c][cc];
  }
}

// ---------------- GEMM1: 256x256 tile, pipelined 4-phase (R9-verified) ----------------
__global__ __launch_bounds__(512, 2) void gemm_qkv4p(
    const __hip_bfloat16* __restrict__ A, const __hip_bfloat16* __restrict__ Bt,
    __hip_bfloat16* __restrict__ Qb, __hip_bfloat16* __restrict__ Kb,
    __hip_bfloat16* __restrict__ Vb) {
  const int K = 2048;
  const int tid = threadIdx.x;
  const int wave = tid >> 6, lane = tid & 63;
  const int l15 = lane & 15, lg = lane >> 4;
  const int bm = blockIdx.x, bn = blockIdx.y;
  const int wm = wave >> 2, wn = wave & 3;

  __shared__ __hip_bfloat16 lds[65536];

  f32x4 acc[8][4] = {};
  const int srow = lane >> 3;
  const int sslot = lane & 7;
  const int scol = (sslot ^ srow) * 8;
  const size_t abase = (size_t)bm * 256 * K;
  const size_t bbase = (size_t)bn * 256 * K;
  const int r3 = l15 & 7;

#define STAGE_HALF(SRC, SBASE, HALF, KO, LBASE)                                  \
  {                                                                              \
    _Pragma("unroll")                                                            \
    for (int l = 0; l < 2; ++l) {                                                \
      int chunk = l * 8 + wave;                                                  \
      int row = chunk * 8 + srow;                                                \
      gload16(SRC + (SBASE) + (size_t)((HALF) * 128 + row) * K + (KO) + scol,    \
              &lds[(LBASE) + chunk * 512]);                                      \
    }                                                                            \
  }

  short8 bfr[4][2];
  short8 af[2][2][2];

#define READ_AF(P, Q, BA)                                                        \
  {                                                                              \
    _Pragma("unroll")                                                            \
    for (int m2 = 0; m2 < 2; ++m2)                                               \
      _Pragma("unroll")                                                          \
      for (int ks = 0; ks < 2; ++ks) {                                           \
        int row = ((Q) * 2 + m2) * 16 + l15;                                     \
        int slot = (ks * 4 + lg) ^ r3;                                           \
        af[P][m2][ks] = *(const short8*)&lds[(BA) + row * 64 + slot * 8];        \
      }                                                                          \
  }

#define READ_BF(BB)                                                              \
  {                                                                              \
    _Pragma("unroll")                                                            \
    for (int ni = 0; ni < 4; ++ni)                                               \
      _Pragma("unroll")                                                          \
      for (int ks = 0; ks < 2; ++ks) {                                           \
        int row = (wn & 1) * 64 + ni * 16 + l15;                                 \
        int slot = (ks * 4 + lg) ^ r3;                                           \
        bfr[ni][ks] = *(const short8*)&lds[(BB) + row * 64 + slot * 8];          \
      }                                                                          \
  }

#define MFMA_Q(Q, P)                                                             \
  {                                                                              \
    __builtin_amdgcn_s_setprio(1);                                               \
    _Pragma("unroll")                                                            \
    for (int ks = 0; ks < 2; ++ks)                                               \
      _Pragma("unroll")                                                          \
      for (int m2 = 0; m2 < 2; ++m2)                                             \
        _Pragma("unroll")                                                        \
        for (int ni = 0; ni < 4; ++ni)                                           \
          acc[(Q) * 2 + m2][ni] = __builtin_amdgcn_mfma_f32_16x16x32_bf16(       \
              af[P][m2][ks], bfr[ni][ks], acc[(Q) * 2 + m2][ni], 0, 0, 0);       \
    __builtin_amdgcn_s_setprio(0);                                               \
  }

#define LGKM0()                                                                  \
  asm volatile("s_waitcnt lgkmcnt(0)" ::: "memory");                             \
  __builtin_amdgcn_sched_barrier(0);

  STAGE_HALF(Bt, bbase, 0, 0, 16384);
  STAGE_HALF(Bt, bbase, 1, 0, 24576);
  STAGE_HALF(A, abase, 0, 0, 0);
  STAGE_HALF(A, abase, 1, 0, 8192);
  STAGE_HALF(Bt, bbase, 0, 64, 49152);
  STAGE_HALF(Bt, bbase, 1, 64, 57344);
  asm volatile("s_waitcnt vmcnt(4)" ::: "memory");
  __builtin_amdgcn_sched_barrier(0);
  __builtin_amdgcn_s_barrier();
  {
    const int bA0 = wm * 8192;
    const int bB0 = 16384 + (wn >> 1) * 8192;
    READ_BF(bB0);
    READ_AF(0, 0, bA0);
  }
  LGKM0();

  for (int t = 0; t < 32; ++t) {
    const int buf = (t & 1) * 32768;
    const int nbuf = buf ^ 32768;
    const int bA = buf + wm * 8192;
    if (t + 1 < 32) STAGE_HALF(A, abase, 0, (t + 1) * 64, nbuf);
    __builtin_amdgcn_s_barrier();
    MFMA_Q(0, 0);
    READ_AF(1, 1, bA);
    LGKM0();
    if (t + 1 < 32) STAGE_HALF(A, abase, 1, (t + 1) * 64, nbuf + 8192);
    __builtin_amdgcn_s_barrier();
    MFMA_Q(1, 1);
    READ_AF(0, 2, bA);
    LGKM0();
    if (t + 2 < 32) STAGE_HALF(Bt, bbase, 0, (t + 2) * 64, buf + 16384);
    __builtin_amdgcn_s_barrier();
    MFMA_Q(2, 0);
    READ_AF(1, 3, bA);
    LGKM0();
    if (t + 2 < 32) STAGE_HALF(Bt, bbase, 1, (t + 2) * 64, buf + 24576);
    if (t < 30) asm volatile("s_waitcnt vmcnt(4)" ::: "memory");
    else        asm volatile("s_waitcnt vmcnt(0)" ::: "memory");
    __builtin_amdgcn_sched_barrier(0);
    __builtin_amdgcn_s_barrier();
    MFMA_Q(3, 1);
    if (t + 1 < 32) {
      const int nbA = nbuf + wm * 8192;
      const int nbB = nbuf + 16384 + (wn >> 1) * 8192;
      READ_BF(nbB);
      READ_AF(0, 0, nbA);
    }
    LGKM0();
  }
#undef STAGE_HALF
#undef READ_AF
#undef READ_BF
#undef MFMA_Q
#undef LGKM0

  __hip_bfloat16* dst; int ldc, coff;
  if (bn < 8)       { dst = Qb; ldc = 2048; coff = bn * 256; }
  else if (bn < 10) { dst = Kb; ldc = 512;  coff = bn * 256 - 2048; }
  else              { dst = Vb; ldc = 512;  coff = bn * 256 - 2560; }
#pragma unroll
  for (int m8 = 0; m8 < 8; ++m8)
#pragma unroll
    for (int ni = 0; ni < 4; ++ni) {
      int row = bm * 256 + wm * 128 + m8 * 16 + lg * 4;
      int col = coff + wn * 64 + ni * 16 + l15;
#pragma unroll
      for (int r = 0; r < 4; ++r)
        dst[(size_t)(row + r) * ldc + col] = __float2bfloat16(acc[m8][ni][r]);
    }
}

// ---------------- GEMM2: C[M][N] f32 = A[M][K] bf16 . Bt[N][K]^T bf16 (verified 128^2) ----------------
__global__ __launch_bounds__(256) void gemm_bt(
    const __hip_bfloat16* __restrict__ A, const __hip_bfloat16* __restrict__ Bt,
    float* __restrict__ C, int M, int N, int K) {
  const int tid = threadIdx.x;
  const int wave = tid >> 6, lane = tid & 63;
  const int l15 = lane & 15, lg = lane >> 4;
  const int bm = blockIdx.x, bn = blockIdx.y;
  const int wm = wave >> 1, wn = wave & 1;

  __shared__ __hip_bfloat16 As[128 * 64];
  __shared__ __hip_bfloat16 Bs[128 * 64];

  f32x4 acc[4][4] = {};
  const int lrow = lane >> 3;
  const int lslot = lane & 7;
  const int scol = (lslot ^ lrow) * 8;
  const size_t abase = (size_t)bm * 128 * K;
  const size_t bbase = (size_t)bn * 128 * K;
  const int r3 = l15 & 7;

  for (int k0 = 0; k0 < K; k0 += 64) {
#pragma unroll
    for (int i = 0; i < 4; ++i) {
      int seg = i * 4 + wave;
      int row = seg * 8 + lrow;
      gload16(A + abase + (size_t)row * K + k0 + scol, &As[seg * 512]);
      gload16(Bt + bbase + (size_t)row * K + k0 + scol, &Bs[seg * 512]);
    }
    __syncthreads();
#pragma unroll
    for (int ks = 0; ks < 2; ++ks) {
      const int slot = (ks * 4 + lg) ^ r3;
      short8 af[4], bf[4];
#pragma unroll
      for (int mi = 0; mi < 4; ++mi)
        af[mi] = *(const short8*)&As[(wm * 64 + mi * 16 + l15) * 64 + slot * 8];
#pragma unroll
      for (int ni = 0; ni < 4; ++ni)
        bf[ni] = *(const short8*)&Bs[(wn * 64 + ni * 16 + l15) * 64 + slot * 8];
#pragma unroll
      for (int mi = 0; mi < 4; ++mi)
#pragma unroll
        for (int ni = 0; ni < 4; ++ni)
          acc[mi][ni] = __builtin_amdgcn_mfma_f32_16x16x32_bf16(af[mi], bf[ni], acc[mi][ni], 0, 0, 0);
    }
    __syncthreads();
  }
#pragma unroll
  for (int mi = 0; mi < 4; ++mi)
#pragma unroll
    for (int ni = 0; ni < 4; ++ni) {
      int row = bm * 128 + wm * 64 + mi * 16 + lg * 4;
      int col = bn * 128 + wn * 64 + ni * 16 + l15;
#pragma unroll
      for (int r = 0; r < 4; ++r)
        C[(size_t)(row + r) * N + col] = acc[mi][ni][r];
    }
}

// ---------------- block-sparse attention: one block per (bi, kvh), 8 waves ----------------
// 256 blocks x 512 threads. Wave w: head = kvh*4 + (w>>1), q-rows [bi*64+(w&1)*32, +32).
// K/V staged ONCE per kb for all 4 heads (was 4x), double-buffered global_load_lds with
// counted vmcnt(4) (T3/T4), both-sides XOR swizzle. Online softmax per wave with defer-max
// (T13): rescale only when __any(pm - m > 8); first kb always triggers (m=-3e38), zeroing
// the l/oacc init. P tile wave-private LDS (no barriers). 2 barriers per kb.
__global__ __launch_bounds__(512, 2) void attn_kernel(
    const __hip_bfloat16* __restrict__ Qb,  // [4096][2048]
    const __hip_bfloat16* __restrict__ Kb,  // [4096][512]
    const __hip_bfloat16* __restrict__ Vt,  // [512][4096]  (channel-major)
    const float* __restrict__ amask,        // [4096]
    __hip_bfloat16* __restrict__ AO)        // [4096][2048]
{
  const int bid = blockIdx.x;
  const int kvh = bid & 3;
  const int bi  = bid >> 2;
  const int tid = threadIdx.x;
  const int wave = tid >> 6, lane = tid & 63;
  const int l15 = lane & 15, lg = lane >> 4;
  const int h  = kvh * 4 + (wave >> 1);
  const int rh = wave & 1;
  const int q0 = bi * 64 + rh * 32;

  // static block selection (matches _select_key_blocks): <=6 blocks, block-uniform
  int sel[6]; int nsel = 0;
  {
    int gtop = bi >> 2;
    for (int j = 0; j <= bi; ++j) {
      bool pick = (j == 0) || (j >= bi - 3) || (((j & 3) == 0) && ((j >> 2) >= gtop - 1));
      if (pick && nsel < 6) sel[nsel++] = j;
    }
  }

  __shared__ __hip_bfloat16 kv[2][16384];  // per buf: K [64][128] at 0, V [128][64] at 8192
  __shared__ __hip_bfloat16 Pl[8][2304];   // per wave: P [32][72]

  // Q fragments: [mi][ks], 32 q-rows x 128 d
  short8 qf[2][4];
#pragma unroll
  for (int mi = 0; mi < 2; ++mi)
#pragma unroll
    for (int ks = 0; ks < 4; ++ks)
      qf[mi][ks] = *(const short8*)(Qb + (size_t)(q0 + mi * 16 + l15) * 2048 +
                                    h * 128 + ks * 32 + lg * 8);

  float m[2][4], l[2][4];
  f32x4 oacc[2][8] = {};
#pragma unroll
  for (int mi = 0; mi < 2; ++mi)
#pragma unroll
    for (int r = 0; r < 4; ++r) { m[mi][r] = -3.0e38f; l[mi][r] = 0.f; }

  // stage K[64][128] + V[128][64] for block KB into kv[BUF] (4 gload16/thread)
#define STAGE_KV(KB, BUF)                                                          \
  {                                                                                \
    _Pragma("unroll")                                                              \
    for (int i = 0; i < 2; ++i) {                                                  \
      int chunk = (i * 8 + wave) * 64 + lane;                                      \
      int row = chunk >> 4, slot = chunk & 15;                                     \
      gload16(Kb + (size_t)((KB) * 64 + row) * 512 + kvh * 128 +                   \
                  ((slot ^ (row & 15)) * 8),                                       \
              &kv[BUF][(i * 8 + wave) * 512]);                                     \
    }                                                                              \
    _Pragma("unroll")                                                              \
    for (int i = 0; i < 2; ++i) {                                                  \
      int chunk = (i * 8 + wave) * 64 + lane;                                      \
      int row = chunk >> 3, slot = chunk & 7;                                      \
      gload16(Vt + (size_t)(kvh * 128 + row) * 4096 + (KB) * 64 +                  \
                  ((slot ^ (row & 7)) * 8),                                        \
              &kv[BUF][8192 + (i * 8 + wave) * 512]);                              \
    }                                                                              \
  }

  STAGE_KV(sel[0], 0);

#pragma unroll
  for (int j = 0; j < 6; ++j) {
    if (j < nsel) {
      const int kb = sel[j];
      if (j + 1 < nsel) {
        STAGE_KV(sel[j + 1], (j + 1) & 1);
        asm volatile("s_waitcnt vmcnt(4)" ::: "memory");
      } else {
        asm volatile("s_waitcnt vmcnt(0)" ::: "memory");
      }
      __builtin_amdgcn_sched_barrier(0);
      __builtin_amdgcn_s_barrier();
      const __hip_bfloat16* kbuf = kv[j & 1];

      // ---- QK^T: sc[mi][nf], 32 MFMA ----
      f32x4 sc[2][4] = {};
#pragma unroll
      for (int nf = 0; nf < 4; ++nf)
#pragma unroll
        for (int ks = 0; ks < 4; ++ks) {
          short8 b = *(const short8*)&kbuf[(nf * 16 + l15) * 128 +
                                           (((ks * 4 + lg) ^ l15) * 8)];
          sc[0][nf] = __builtin_amdgcn_mfma_f32_16x16x32_bf16(qf[0][ks], b, sc[0][nf], 0, 0, 0);
          sc[1][nf] = __builtin_amdgcn_mfma_f32_16x16x32_bf16(qf[1][ks], b, sc[1][nf], 0, 0, 0);
        }

      // ---- mask + scale ----
      float am[4];
#pragma unroll
      for (int nf = 0; nf < 4; ++nf)
        am[nf] = (1.0f - amask[kb * 64 + nf * 16 + l15]) * NEGV;
#pragma unroll
      for (int mi = 0; mi < 2; ++mi)
#pragma unroll
        for (int nf = 0; nf < 4; ++nf) {
          int keyl = nf * 16 + l15;
#pragma unroll
          for (int r = 0; r < 4; ++r) {
            float s = sc[mi][nf][r] * SCALE + am[nf];
            if (kb == bi) {
              int qrow = rh * 32 + mi * 16 + lg * 4 + r;
              if (keyl > qrow) s = NEGV;
            }
            sc[mi][nf][r] = s;
          }
        }

      // ---- row max (over nf, then over the 16-lane l15 group) ----
      float pm[2][4];
#pragma unroll
      for (int mi = 0; mi < 2; ++mi)
#pragma unroll
        for (int r = 0; r < 4; ++r) {
          float v = fmaxf(fmaxf(sc[mi][0][r], sc[mi][1][r]),
                          fmaxf(sc[mi][2][r], sc[mi][3][r]));
          v = fmaxf(v, __shfl_xor(v, 1)); v = fmaxf(v, __shfl_xor(v, 2));
          v = fmaxf(v, __shfl_xor(v, 4)); v = fmaxf(v, __shfl_xor(v, 8));
          pm[mi][r] = v;
        }

      // ---- online-softmax state update (defer-max, THR=8) ----
      bool need = false;
#pragma unroll
      for (int mi = 0; mi < 2; ++mi)
#pragma unroll
        for (int r = 0; r < 4; ++r) need |= (pm[mi][r] - m[mi][r] > 8.0f);
      if (__any(need)) {
#pragma unroll
        for (int mi = 0; mi < 2; ++mi)
#pragma unroll
          for (int r = 0; r < 4; ++r) {
            float mn = fmaxf(m[mi][r], pm[mi][r]);
            float scl = __expf(m[mi][r] - mn);      // ==1 when unchanged; ==0 on first kb
            l[mi][r] *= scl;
#pragma unroll
            for (int df = 0; df < 8; ++df) oacc[mi][df][r] *= scl;
            m[mi][r] = mn;
          }
      }

      // ---- P = exp(s - m), row-sum, write wave-private P tile ----
#pragma unroll
      for (int mi = 0; mi < 2; ++mi)
#pragma unroll
        for (int r = 0; r < 4; ++r) {
          float rs = 0.f;
#pragma unroll
          for (int nf = 0; nf < 4; ++nf) {
            float p = __expf(sc[mi][nf][r] - m[mi][r]);
            rs += p;
            Pl[wave][(mi * 16 + lg * 4 + r) * 72 + nf * 16 + l15] = __float2bfloat16(p);
          }
          rs += __shfl_xor(rs, 1); rs += __shfl_xor(rs, 2);
          rs += __shfl_xor(rs, 4); rs += __shfl_xor(rs, 8);
          l[mi][r] += rs;
        }

      // ---- PV: oacc[mi][df] += P(32x64) . V(64x128), 32 MFMA ----
      short8 af2[2][2];
#pragma unroll
      for (int mi = 0; mi < 2; ++mi)
#pragma unroll
        for (int ks = 0; ks < 2; ++ks)
          af2[mi][ks] = *(const short8*)&Pl[wave][(mi * 16 + l15) * 72 + ks * 32 + lg * 8];
#pragma unroll
      for (int df = 0; df < 8; ++df)
#pragma unroll
        for (int ks = 0; ks < 2; ++ks) {
          short8 vb = *(const short8*)&kbuf[8192 + (df * 16 + l15) * 64 +
                                            (((ks * 4 + lg) ^ (l15 & 7)) * 8)];
          oacc[0][df] = __builtin_amdgcn_mfma_f32_16x16x32_bf16(af2[0][ks], vb, oacc[0][df], 0, 0, 0);
          oacc[1][df] = __builtin_amdgcn_mfma_f32_16x16x32_bf16(af2[1][ks], vb, oacc[1][df], 0, 0, 0);
        }
      __builtin_amdgcn_s_barrier();   // release buffer for kb+2's stage
    }
  }
#undef STAGE_KV

  // ---- epilogue: normalize and write AO ----
#pragma unroll
  for (int mi = 0; mi < 2; ++mi) {
    float inv[4];
#pragma unroll
    for (int r = 0; r < 4; ++r) inv[r] = 1.0f / l[mi][r];
#pragma unroll
    for (int df = 0; df < 8; ++df)
#pragma unroll
      for (int r = 0; r < 4; ++r) {
        int qrow = q0 + mi * 16 + lg * 4 + r;
        AO[(size_t)qrow * 2048 + h * 128 + df * 16 + l15] =
            __float2bfloat16(oacc[mi][df][r] * inv[r]);
      }
  }
}

// ---------------- launch ----------------
extern "C" void kernel_launch(void* const* d_in, const int* in_sizes, int n_in,
                              void* d_out, int out_size, void* d_ws, size_t ws_size,
                              hipStream_t stream) {
  const float* hidden = (const float*)d_in[0];
  const float* cosb   = (const float*)d_in[1];
  const float* sinb   = (const float*)d_in[2];
  const float* Wq     = (const float*)d_in[3];
  const float* Wk     = (const float*)d_in[4];
  const float* Wv     = (const float*)d_in[5];
  const float* Wo     = (const float*)d_in[6];
  const float* amask  = (const float*)d_in[7];

  char* ws = (char*)d_ws;
  __hip_bfloat16* Xb   = (__hip_bfloat16*)(ws);               // 16,777,216 B  [4096][2048]
  __hip_bfloat16* Wt   = (__hip_bfloat16*)(ws + 16777216);    // 12,582,912 B  [3072][2048]
  __hip_bfloat16* Wot  = (__hip_bfloat16*)(ws + 29360128);    //  8,388,608 B  [2048][2048]
  __hip_bfloat16* Qb   = (__hip_bfloat16*)(ws + 37748736);    // 16,777,216 B  [4096][2048]
  __hip_bfloat16* Kb   = (__hip_bfloat16*)(ws + 54525952);    //  4,194,304 B  [4096][512]
  __hip_bfloat16* Vb   = (__hip_bfloat16*)(ws + 58720256);    //  4,194,304 B  [4096][512]
  __hip_bfloat16* Vt   = (__hip_bfloat16*)(ws + 62914560);    //  4,194,304 B  [512][4096]
  __hip_bfloat16* AO   = Xb;  // Xb dead after gemm_qkv4p; reuse for attention output

  prep_all<<<10752, 256, 0, stream>>>(hidden, Wq, Wk, Wv, Wo, Xb, Wt, Wot);

  gemm_qkv4p<<<dim3(16, 12), 512, 0, stream>>>(Xb, Wt, Qb, Kb, Vb);

  postproc<<<1792, 256, 0, stream>>>(cosb, sinb, Qb, Kb, Vb, Vt);

  attn_kernel<<<256, 512, 0, stream>>>(Qb, Kb, Vt, amask, AO);

  gemm_bt<<<dim3(32, 16), 256, 0, stream>>>(AO, Wot, (float*)d_out, 4096, 2048, 2048);
}